// Round 19
// baseline (2671.583 us; speedup 1.0000x reference)
//
#include <hip/hip_runtime.h>
#include <math.h>

#define B_  64
#define T_  50
#define S_  50
#define U_  1024
#define E_  100
#define V_  30001
#define U4_ 4096
#define VP_ 30080       // V padded to a multiple of 128 for bf16 staging
#define HSTR_ 65600     // h-plane stride: 64*1024 + 64 pad floats

typedef __bf16 bf16_t;
typedef bf16_t bf16x8 __attribute__((ext_vector_type(8)));
typedef float  f32x4  __attribute__((ext_vector_type(4)));
typedef unsigned long long u64_t;

// ---------------------------------------------------------------------------
// Coherence-point accessors (SYSTEM scope -> sc0+sc1; proven r11-r18).
// ---------------------------------------------------------------------------
__device__ __forceinline__ void scstore8(float* p, float x, float y) {
    union { u64_t u; float2 f; } c; c.f = make_float2(x, y);
    __hip_atomic_store((u64_t*)p, c.u, __ATOMIC_RELAXED,
                       __HIP_MEMORY_SCOPE_SYSTEM);
}
__device__ __forceinline__ float2 scload8(const float* p) {
    u64_t v = __hip_atomic_load((const u64_t*)p, __ATOMIC_RELAXED,
                                __HIP_MEMORY_SCOPE_SYSTEM);
    union { u64_t u; float2 f; } c; c.u = v; return c.f;
}
__device__ __forceinline__ unsigned scload_u(const unsigned* p) {
    return __hip_atomic_load(p, __ATOMIC_RELAXED, __HIP_MEMORY_SCOPE_SYSTEM);
}
__device__ __forceinline__ void scadd_u(unsigned* p) {
    __hip_atomic_fetch_add(p, 1u, __ATOMIC_RELAXED, __HIP_MEMORY_SCOPE_SYSTEM);
}
__device__ __forceinline__ void vm_drain() {
    asm volatile("s_waitcnt vmcnt(0)" ::: "memory");
}
__device__ __forceinline__ void cbar() { asm volatile("" ::: "memory"); }

__global__ void add_inplace(float* __restrict__ dst, const float* __restrict__ src, int n)
{
    int i = blockIdx.x * blockDim.x + threadIdx.x;
    if (i < n) dst[i] += src[i];
}

// x_emb padded to K=128: cols 0..99 = emb[token], col 100 = 1.0, rest 0.
__global__ void gather_emb_pad(const int* __restrict__ tokens,
                               const float* __restrict__ emb,
                               float* __restrict__ xe)
{
    const int r = blockIdx.x;
    const int e = threadIdx.x;
    float v;
    if (e < E_)       v = emb[(size_t)tokens[r] * E_ + e];
    else if (e == E_) v = 1.f;
    else              v = 0.f;
    xe[(size_t)r * 128 + e] = v;
}

// wx_pad[128][4096]: rows 0..99 = Wx top, row 100 = bvec, rows 101..127 = 0.
__global__ void pad_wx(const float* __restrict__ Wx,
                       const float* __restrict__ bvec,
                       float* __restrict__ dst)
{
    const int col = blockIdx.x * 256 + threadIdx.x;
    const int row = blockIdx.y;
    float v;
    if (row < E_)       v = Wx[(size_t)row * U4_ + col];
    else if (row == E_) v = bvec[col];
    else                v = 0.f;
    dst[(size_t)row * U4_ + col] = v;
}

// ---------------------------------------------------------------------------
// Wo [1024][30001] f32 -> wo_t [VP_][1024] bf16 (transposed, tiled via LDS).
// ---------------------------------------------------------------------------
__global__ __launch_bounds__(256) void transpose_wo(
    const float* __restrict__ wo, bf16_t* __restrict__ dst)
{
    __shared__ bf16_t tile[64][72];
    const int c0 = blockIdx.x * 64;
    const int k0 = blockIdx.y * 64;
    const int tx = threadIdx.x & 63, ty = threadIdx.x >> 6;

#pragma unroll
    for (int kk = ty; kk < 64; kk += 4) {
        const int col = c0 + tx;
        float v = (col < V_) ? wo[(size_t)(k0 + kk) * V_ + col] : 0.f;
        tile[kk][tx] = (bf16_t)v;
    }
    __syncthreads();
#pragma unroll
    for (int cc = ty; cc < 64; cc += 4)
        dst[(size_t)(c0 + cc) * 1024 + k0 + tx] = tile[tx][cc];
}

// ---------------------------------------------------------------------------
// Split-bf16 3-pass MFMA GEMM (r15-proven): C = A@B, rel err ~2^-18.
// ---------------------------------------------------------------------------
template <int OUT>
__global__ __launch_bounds__(256) void gemm_mfma_split(
    const float* __restrict__ A, int lda,
    const float* __restrict__ Bm, int ldb,
    float* __restrict__ C, int ldc, int K)
{
    __shared__ bf16_t As_h[128][40];
    __shared__ bf16_t As_l[128][40];
    __shared__ bf16_t Bs_h[128][40];
    __shared__ bf16_t Bs_l[128][40];

    const int n0  = blockIdx.x * 128;
    const int m0  = blockIdx.y * 128;
    const int tid = threadIdx.x;
    const int wave = tid >> 6, lane = tid & 63;
    const int wr = wave >> 1, wc = wave & 1;
    const int lr = lane & 15;
    const int lk = lane >> 4;

    f32x4 acc[4][4] = {};

    const int ar  = tid >> 1, ak = (tid & 1) * 16;
    const int bk0 = (tid >> 5) * 4, bc = (tid & 31) * 4;

    for (int k0 = 0; k0 < K; k0 += 32) {
        {
            const float* ap = &A[(size_t)(m0 + ar) * lda + k0 + ak];
            bf16x8 h0v, l0v, h1v, l1v;
#pragma unroll
            for (int q = 0; q < 2; ++q) {
                float4 v0 = *(const float4*)&ap[q * 8];
                float4 v1 = *(const float4*)&ap[q * 8 + 4];
                float xs[8] = {v0.x, v0.y, v0.z, v0.w, v1.x, v1.y, v1.z, v1.w};
#pragma unroll
                for (int e = 0; e < 8; ++e) {
                    bf16_t h = (bf16_t)xs[e];
                    if (q == 0) { h0v[e] = h; l0v[e] = (bf16_t)(xs[e] - (float)h); }
                    else        { h1v[e] = h; l1v[e] = (bf16_t)(xs[e] - (float)h); }
                }
            }
            *(bf16x8*)&As_h[ar][ak]     = h0v;
            *(bf16x8*)&As_h[ar][ak + 8] = h1v;
            *(bf16x8*)&As_l[ar][ak]     = l0v;
            *(bf16x8*)&As_l[ar][ak + 8] = l1v;
        }
        {
#pragma unroll
            for (int kk = 0; kk < 4; ++kk) {
                float4 v = *(const float4*)&Bm[(size_t)(k0 + bk0 + kk) * ldb + n0 + bc];
                float xs[4] = {v.x, v.y, v.z, v.w};
#pragma unroll
                for (int i = 0; i < 4; ++i) {
                    bf16_t h = (bf16_t)xs[i];
                    Bs_h[bc + i][bk0 + kk] = h;
                    Bs_l[bc + i][bk0 + kk] = (bf16_t)(xs[i] - (float)h);
                }
            }
        }
        __syncthreads();

        bf16x8 ah[4], alv[4], bh[4], bl[4];
#pragma unroll
        for (int m = 0; m < 4; ++m) {
            ah[m]  = *(const bf16x8*)&As_h[wr * 64 + m * 16 + lr][lk * 8];
            alv[m] = *(const bf16x8*)&As_l[wr * 64 + m * 16 + lr][lk * 8];
        }
#pragma unroll
        for (int n = 0; n < 4; ++n) {
            bh[n] = *(const bf16x8*)&Bs_h[wc * 64 + n * 16 + lr][lk * 8];
            bl[n] = *(const bf16x8*)&Bs_l[wc * 64 + n * 16 + lr][lk * 8];
        }
#pragma unroll
        for (int m = 0; m < 4; ++m)
#pragma unroll
            for (int n = 0; n < 4; ++n) {
                acc[m][n] = __builtin_amdgcn_mfma_f32_16x16x32_bf16(ah[m],  bh[n], acc[m][n], 0, 0, 0);
                acc[m][n] = __builtin_amdgcn_mfma_f32_16x16x32_bf16(ah[m],  bl[n], acc[m][n], 0, 0, 0);
                acc[m][n] = __builtin_amdgcn_mfma_f32_16x16x32_bf16(alv[m], bh[n], acc[m][n], 0, 0, 0);
            }
        __syncthreads();
    }

#pragma unroll
    for (int m = 0; m < 4; ++m) {
        const int row = m0 + wr * 64 + m * 16 + lk * 4;
#pragma unroll
        for (int n = 0; n < 4; ++n) {
            const int col = n0 + wc * 64 + n * 16 + lr;
#pragma unroll
            for (int r = 0; r < 4; ++r) {
                if (OUT == 0)
                    C[(size_t)(row + r) * ldc + col] = acc[m][n][r];
                else
                    ((bf16_t*)C)[(size_t)(row + r) * ldc + col] = (bf16_t)acc[m][n][r];
            }
        }
    }
}

// ---------------------------------------------------------------------------
// Split-K GEMM for t=0: zp[(ks*64+b)*4096+n] = sum_{k in 256-slice} h0@Uh.
// ---------------------------------------------------------------------------
__global__ __launch_bounds__(256) void zgemm_partial(
    const float* __restrict__ A, int lda,
    const float* __restrict__ Bm,
    float* __restrict__ zp)
{
    __shared__ float As[64][17];
    __shared__ float Bs[16][68];

    const int n0     = blockIdx.x * 64;
    const int ks     = blockIdx.y;
    const int k_base = ks * 256;
    const int tid    = threadIdx.x;
    const int tx     = tid & 15, ty = tid >> 4;

    float acc[4][4];
#pragma unroll
    for (int i = 0; i < 4; ++i)
#pragma unroll
        for (int j = 0; j < 4; ++j) acc[i][j] = 0.f;

    const int ra = tid >> 2, ca = (tid & 3) * 4;
    const int rb = tid >> 4, cb = (tid & 15) * 4;

    for (int kt = 0; kt < 16; ++kt) {
        const int k0 = k_base + kt * 16;
        float4 av = *(const float4*)&A[(size_t)ra * lda + k0 + ca];
        As[ra][ca + 0] = av.x;
        As[ra][ca + 1] = av.y;
        As[ra][ca + 2] = av.z;
        As[ra][ca + 3] = av.w;
        float4 bv = *(const float4*)&Bm[(size_t)(k0 + rb) * U4_ + n0 + cb];
        *(float4*)&Bs[rb][cb] = bv;
        __syncthreads();
#pragma unroll
        for (int kk = 0; kk < 16; ++kk) {
            float a_[4];
#pragma unroll
            for (int i = 0; i < 4; ++i) a_[i] = As[ty * 4 + i][kk];
            float4 bq = *(const float4*)&Bs[kk][tx * 4];
            float b_[4] = {bq.x, bq.y, bq.z, bq.w};
#pragma unroll
            for (int i = 0; i < 4; ++i)
#pragma unroll
                for (int j = 0; j < 4; ++j)
                    acc[i][j] = fmaf(a_[i], b_[j], acc[i][j]);
        }
        __syncthreads();
    }

#pragma unroll
    for (int i = 0; i < 4; ++i)
        *(float4*)&zp[((size_t)ks * 64 + ty * 4 + i) * U4_ + n0 + tx * 4] =
            make_float4(acc[i][0], acc[i][1], acc[i][2], acc[i][3]);
}

// ---------------------------------------------------------------------------
// Post-loop ctx reconstruction: hc_all[b][t][1024+u] = sum_s align[b][t][s] *
// memory[b][s][u]. One block per batch.
// ---------------------------------------------------------------------------
__global__ __launch_bounds__(512) void ctx_recon(
    const float* __restrict__ align_all,  // [64][50][64]
    const float* __restrict__ memory,     // [64][50][1024]
    float* __restrict__ hc_all)           // [64][50][2048]
{
    __shared__ float alds[T_ * 64];
    const int b = blockIdx.x, tid = threadIdx.x;
    for (int i = tid; i < T_ * 64; i += 512)
        alds[i] = align_all[(size_t)b * T_ * 64 + i];
    __syncthreads();
    const int u2 = tid * 2;
    for (int t0 = 0; t0 < T_; t0 += 10) {
        float ax[10], ay[10];
#pragma unroll
        for (int q = 0; q < 10; ++q) { ax[q] = 0.f; ay[q] = 0.f; }
        for (int s = 0; s < S_; ++s) {
            float2 mv = *(const float2*)&memory[((size_t)b * S_ + s) * U_ + u2];
#pragma unroll
            for (int q = 0; q < 10; ++q) {
                float a = alds[(t0 + q) * 64 + s];
                ax[q] = fmaf(a, mv.x, ax[q]);
                ay[q] = fmaf(a, mv.y, ay[q]);
            }
        }
#pragma unroll
        for (int q = 0; q < 10; ++q)
            *(float2*)&hc_all[((size_t)b * T_ + t0 + q) * 2048 + U_ + u2] =
                make_float2(ax[q], ay[q]);
    }
}

// ---------------------------------------------------------------------------
// Persistent decoder loop v13 — M2-FACTORED recurrence (chain shortened):
//   z(t) = zemb(t) + h(t-1)@Wcomb_top' + align(t-1)@M2[b]
// Phase A (256 blocks = 64 nt x 4 ks of 256k): h-half GEMM only (K=1024).
// BC (blocks<64): gates (+local zal) -> h publish -> scores/softmax -> align
//   -> zal(t+1) = align@M2 (K=50, local, overlaps next A phase). NO ctx in
//   loop; align archived, ctx rebuilt post-loop.
// Flags: [g*32] g<16 zp-done (16 adds each); [512+g*32] g<8 h-done (8 adds).
// LDS: wfr 65536 + tr 17408 + hs 4096 + sc 256 + al 256 = 87552 B.
// ---------------------------------------------------------------------------
__global__ __launch_bounds__(512) void decoder_loop13(
    const float* __restrict__ zemb,    // [3200][4096] (d_out scratch)
    const float* __restrict__ Wcomb,   // [2048][4096] (d_out scratch; top'=rows 0..1023)
    const float* __restrict__ M2,      // [3200][4096] (d_out scratch)
    const float* __restrict__ keys,    // [64][50][1024]
    const float* __restrict__ memory,  // [64][50][1024]
    const float* __restrict__ c0,
    float* __restrict__ hbuf,          // [50][HSTR_] (d_out scratch)
    float* __restrict__ zp,            // [4][64][4096] (sc-ops only)
    float* __restrict__ hc_all,        // [64][50][2048] (plain; h half)
    float* __restrict__ align_all,     // [64][50][64] (plain)
    unsigned* flags)
{
    static __shared__ __attribute__((aligned(16))) char smem[87552];
    bf16_t* wfr = (bf16_t*)smem;                    // 65536 B frag store
    float*  tr  = (float*)(smem + 65536);           // [64][68] transpose
    float*  hs  = (float*)(smem + 82944);           // 1024
    float*  sc  = (float*)(smem + 87040);           // 64
    float*  al  = (float*)(smem + 87296);           // 64

    const int beta = blockIdx.x;
    const int tid  = threadIdx.x;

    const int nt = beta & 63, ks = beta >> 6;   // 64 col-tiles x 4 k-slices
    const int koff = ks * 256;
    const int c0c  = nt * 64;

    // ---- pack Wcomb_top' slice [256 k][64 cols] -> LDS fragments (once) ----
    for (int i = tid; i < 256 * 64; i += 512) {
        const int k = i >> 6, col = i & 63;
        const float w = Wcomb[(size_t)(koff + k) * U4_ + c0c + col];
        const bf16_t hi = (bf16_t)w;
        const bf16_t lo = (bf16_t)(w - (float)hi);
        const int ntile = col >> 4, lane_lo = col & 15;
        const int kk = k >> 5, kr = k & 31;
        const int lane = (kr >> 3) * 16 + lane_lo, j = kr & 7;
        const int base = ((ntile * 8 + kk) * 2) * 512 + lane * 8 + j;
        wfr[base]       = hi;
        wfr[base + 512] = lo;
    }

    const int b  = beta;
    const int u2 = tid * 2;
    float creg[2] = {0.f, 0.f};
    float zalx[4] = {0.f, 0.f, 0.f, 0.f};   // align(t-1)@M2 term (t=0: 0)
    float zaly[4] = {0.f, 0.f, 0.f, 0.f};
    if (beta < 64) {
        float2 cv = *(const float2*)&c0[b * U_ + u2];
        creg[0] = cv.x;
        creg[1] = cv.y;
    }
    __syncthreads();

    // phase-A indices (8 waves; wave: rows mt*16..+16, n-tiles ntb, ntb+1)
    const int w  = tid >> 6, l = tid & 63;
    const int mt = w >> 1, ntb = (w & 1) * 2;
    const int arow = mt * 16 + (l & 15);
    const int aq   = l >> 4;
    const size_t abase = (size_t)arow * U_ + koff + aq * 8;

    for (int t = 0; t < T_; ++t) {
        // ---------------- phase A (t>=1): zp = hbuf[t-1] @ Wtop' (MFMA) -----
        if (t) {
            {   // wait for h(t-1): all 8 h-groups >= 8t
                const unsigned tgt = 8u * (unsigned)t;
                if (tid < 8) {
                    const unsigned* f = &flags[512 + tid * 32];
                    while (scload_u(f) < tgt) __builtin_amdgcn_s_sleep(1);
                }
                __syncthreads();
                cbar();
            }

            const float* ap = &hbuf[(size_t)(t - 1) * HSTR_ + abase];

            f32x4 acc[2] = {};
#pragma unroll
            for (int kk = 0; kk < 8; ++kk) {
                float4 a0 = *(const float4*)&ap[kk * 32];
                float4 a1 = *(const float4*)&ap[kk * 32 + 4];
                float xs[8] = {a0.x, a0.y, a0.z, a0.w, a1.x, a1.y, a1.z, a1.w};
                bf16x8 ah, alv;
#pragma unroll
                for (int e = 0; e < 8; ++e) {
                    bf16_t h = (bf16_t)xs[e];
                    ah[e]  = h;
                    alv[e] = (bf16_t)(xs[e] - (float)h);
                }
#pragma unroll
                for (int nn = 0; nn < 2; ++nn) {
                    const int fb2 = (((ntb + nn) * 8 + kk) * 2) * 512 + l * 8;
                    bf16x8 bh = *(const bf16x8*)&wfr[fb2];
                    bf16x8 bl = *(const bf16x8*)&wfr[fb2 + 512];
                    acc[nn] = __builtin_amdgcn_mfma_f32_16x16x32_bf16(ah, bh, acc[nn], 0, 0, 0);
                    acc[nn] = __builtin_amdgcn_mfma_f32_16x16x32_bf16(ah, bl, acc[nn], 0, 0, 0);
                    acc[nn] = __builtin_amdgcn_mfma_f32_16x16x32_bf16(alv, bh, acc[nn], 0, 0, 0);
                }
            }

            // acc -> LDS transpose (C/D map: col=l&15, row=(l>>4)*4+reg)
#pragma unroll
            for (int nn = 0; nn < 2; ++nn)
#pragma unroll
                for (int rr = 0; rr < 4; ++rr)
                    tr[(mt * 16 + (l >> 4) * 4 + rr) * 68 + (ntb + nn) * 16 + (l & 15)] =
                        acc[nn][rr];
            __syncthreads();

            // vectorized sc-stores of zp
            {
                const int zb = tid >> 3, cg = (tid & 7) * 8;
                float4 r0 = *(const float4*)&tr[zb * 68 + cg];
                float4 r1 = *(const float4*)&tr[zb * 68 + cg + 4];
                float* zrow = &zp[((size_t)(ks * 64 + zb)) * U4_ + c0c + cg];
                scstore8(zrow + 0, r0.x, r0.y);
                scstore8(zrow + 2, r0.z, r0.w);
                scstore8(zrow + 4, r1.x, r1.y);
                scstore8(zrow + 6, r1.z, r1.w);
            }
            vm_drain();
            __syncthreads();
            if (tid == 0) scadd_u(&flags[(beta & 15) * 32]);   // zp group flag
        }

        // ---------------- phase BC: gates + attention (blocks < 64) ---------
        if (beta < 64) {
            if (t) {
                const unsigned tgt = 16u * (unsigned)t;
                if (tid < 16) {
                    const unsigned* f = &flags[tid * 32];
                    while (scload_u(f) < tgt) __builtin_amdgcn_s_sleep(1);
                }
                __syncthreads();
                cbar();
            }

            const float* ze = &zemb[((size_t)b * T_ + t) * U4_];
            float zgx[4], zgy[4];
#pragma unroll
            for (int g = 0; g < 4; ++g) {
                float2 a = *(const float2*)&ze[g * U_ + u2];   // plain cached
                zgx[g] = a.x + zalx[g];
                zgy[g] = a.y + zaly[g];
            }
#pragma unroll
            for (int s = 0; s < 4; ++s) {
#pragma unroll
                for (int g = 0; g < 4; ++g) {
                    float2 v = scload8(&zp[((size_t)s * 64 + b) * U4_ + g * U_ + u2]);
                    zgx[g] += v.x;
                    zgy[g] += v.y;
                }
            }

            const float six = 1.f / (1.f + expf(-zgx[0]));
            const float sfx = 1.f / (1.f + expf(-zgx[1]));
            const float tgx = tanhf(zgx[2]);
            const float sox = 1.f / (1.f + expf(-zgx[3]));
            const float cnx = sfx * creg[0] + six * tgx;
            creg[0] = cnx;
            const float hnx = sox * tanhf(cnx);

            const float siy = 1.f / (1.f + expf(-zgy[0]));
            const float sfy = 1.f / (1.f + expf(-zgy[1]));
            const float tgy = tanhf(zgy[2]);
            const float soy = 1.f / (1.f + expf(-zgy[3]));
            const float cny = sfy * creg[1] + siy * tgy;
            creg[1] = cny;
            const float hny = soy * tanhf(cny);

            // publish h fast (critical path), archive h (plain)
            hs[u2]     = hnx;
            hs[u2 + 1] = hny;
            scstore8(&hbuf[(size_t)t * HSTR_ + b * U_ + u2], hnx, hny);
            *(float2*)&hc_all[((size_t)b * T_ + t) * 2048 + u2] =
                make_float2(hnx, hny);
            vm_drain();
            __syncthreads();
            if (tid == 0) scadd_u(&flags[512 + (b & 7) * 32]);  // h group flag

            // ---- off-critical-path: scores -> softmax -> align -> zal ------
            const int lane = tid & 63, wv = tid >> 6;
            for (int s = wv; s < S_; s += 8) {
                const float* kp = &keys[((size_t)b * S_ + s) * U_ + lane * 16];
                const float* hp = &hs[lane * 16];
                float p = 0.f;
#pragma unroll
                for (int q = 0; q < 4; ++q) {
                    float4 kv = *(const float4*)&kp[q * 4];
                    float4 hv = *(const float4*)&hp[q * 4];
                    p = fmaf(hv.x, kv.x, p);
                    p = fmaf(hv.y, kv.y, p);
                    p = fmaf(hv.z, kv.z, p);
                    p = fmaf(hv.w, kv.w, p);
                }
#pragma unroll
                for (int off = 32; off > 0; off >>= 1)
                    p += __shfl_xor(p, off);
                if (lane == 0) sc[s] = p;
            }
            __syncthreads();

            if (tid < 64) {
                float v = (tid < S_) ? sc[tid] : -INFINITY;
                float m = v;
#pragma unroll
                for (int off = 32; off > 0; off >>= 1)
                    m = fmaxf(m, __shfl_xor(m, off));
                float e = (tid < S_) ? expf(v - m) : 0.f;
                float ssum = e;
#pragma unroll
                for (int off = 32; off > 0; off >>= 1)
                    ssum += __shfl_xor(ssum, off);
                al[tid] = (tid < S_) ? e / ssum : 0.f;
            }
            __syncthreads();

            // archive align (for post-loop ctx reconstruction)
            if (tid < 64)
                align_all[((size_t)b * T_ + t) * 64 + tid] = al[tid];

            // zal(t+1) = align @ M2[b]  (K=50, local; overlaps next A phase)
#pragma unroll
            for (int g = 0; g < 4; ++g) { zalx[g] = 0.f; zaly[g] = 0.f; }
            const float* m2b = &M2[(size_t)b * S_ * U4_];
            for (int s = 0; s < S_; ++s) {
                const float a = al[s];
                const float* mr = &m2b[(size_t)s * U4_];
#pragma unroll
                for (int g = 0; g < 4; ++g) {
                    float2 mv = *(const float2*)&mr[g * U_ + u2];
                    zalx[g] = fmaf(a, mv.x, zalx[g]);
                    zaly[g] = fmaf(a, mv.y, zaly[g]);
                }
            }
        }
    }
}

// ---------------------------------------------------------------------------
// bf16 MFMA GEMM for Wo, DOUBLE-BUFFERED: C = A[3200][1024] @ Bt^T + bias.
// ---------------------------------------------------------------------------
__global__ __launch_bounds__(256) void gemm_wo_mfma3(
    const bf16_t* __restrict__ A,
    const bf16_t* __restrict__ Bt,
    const float*  __restrict__ bias,
    float* __restrict__ C)
{
    __shared__ bf16_t As[2][128][40];
    __shared__ bf16_t Bs[2][128][40];

    const int n0  = blockIdx.x * 128;
    const int m0  = blockIdx.y * 128;
    const int tid = threadIdx.x;
    const int wave = tid >> 6, lane = tid & 63;
    const int wr = wave >> 1, wc = wave & 1;
    const int lr = lane & 15;
    const int lk = lane >> 4;

    f32x4 acc[4][4] = {};

    const int ar = tid >> 1, ak = (tid & 1) * 16;
    const bf16_t* apb = &A[(size_t)(m0 + ar) * U_ + ak];
    const bf16_t* bpb = &Bt[(size_t)(n0 + ar) * U_ + ak];

    {
        *(bf16x8*)&As[0][ar][ak]     = *(const bf16x8*)&apb[0];
        *(bf16x8*)&As[0][ar][ak + 8] = *(const bf16x8*)&apb[8];
        *(bf16x8*)&Bs[0][ar][ak]     = *(const bf16x8*)&bpb[0];
        *(bf16x8*)&Bs[0][ar][ak + 8] = *(const bf16x8*)&bpb[8];
    }
    __syncthreads();

    for (int k0 = 0; k0 < U_; k0 += 32) {
        const int cur = (k0 >> 5) & 1;
        bf16x8 na0, na1, nb0, nb1;
        const bool more = (k0 + 32 < U_);
        if (more) {
            na0 = *(const bf16x8*)&apb[k0 + 32];
            na1 = *(const bf16x8*)&apb[k0 + 40];
            nb0 = *(const bf16x8*)&bpb[k0 + 32];
            nb1 = *(const bf16x8*)&bpb[k0 + 40];
        }

        bf16x8 af[4], bf[4];
#pragma unroll
        for (int m = 0; m < 4; ++m)
            af[m] = *(const bf16x8*)&As[cur][wr * 64 + m * 16 + lr][lk * 8];
#pragma unroll
        for (int n = 0; n < 4; ++n)
            bf[n] = *(const bf16x8*)&Bs[cur][wc * 64 + n * 16 + lr][lk * 8];
#pragma unroll
        for (int m = 0; m < 4; ++m)
#pragma unroll
            for (int n = 0; n < 4; ++n)
                acc[m][n] = __builtin_amdgcn_mfma_f32_16x16x32_bf16(
                    af[m], bf[n], acc[m][n], 0, 0, 0);

        if (more) {
            *(bf16x8*)&As[cur ^ 1][ar][ak]     = na0;
            *(bf16x8*)&As[cur ^ 1][ar][ak + 8] = na1;
            *(bf16x8*)&Bs[cur ^ 1][ar][ak]     = nb0;
            *(bf16x8*)&Bs[cur ^ 1][ar][ak + 8] = nb1;
        }
        __syncthreads();
    }

#pragma unroll
    for (int m = 0; m < 4; ++m) {
        const int row = m0 + wr * 64 + m * 16 + lk * 4;
#pragma unroll
        for (int n = 0; n < 4; ++n) {
            const int col = n0 + wc * 64 + n * 16 + lr;
            if (col < V_) {
                const float bb = bias[col];
#pragma unroll
                for (int r = 0; r < 4; ++r)
                    C[(size_t)(row + r) * V_ + col] = acc[m][n][r] + bb;
            }
        }
    }
}

// ---------------------------------------------------------------------------
extern "C" void kernel_launch(void* const* d_in, const int* in_sizes, int n_in,
                              void* d_out, int out_size, void* d_ws, size_t ws_size,
                              hipStream_t stream)
{
    const int*   tokens = (const int*)  d_in[0];
    const float* memory = (const float*)d_in[1];
    const float* h0     = (const float*)d_in[2];
    const float* c0     = (const float*)d_in[3];
    const float* emb    = (const float*)d_in[4];
    const float* Wx     = (const float*)d_in[5];
    const float* Uh     = (const float*)d_in[6];
    const float* bvec   = (const float*)d_in[7];
    const float* Wm     = (const float*)d_in[8];
    const float* Wa     = (const float*)d_in[9];
    const float* Wo     = (const float*)d_in[10];
    const float* bo     = (const float*)d_in[11];
    float* out = (float*)d_out;

    // ---- workspace layout (float units) ----
    float* ws = (float*)d_ws;
    size_t off = 0;
    float*   keys    = ws + off; off += (size_t)B_ * S_ * U_;    // 13.11 MB
    float*   hc_all  = ws + off; off += (size_t)B_ * T_ * 2048;  // 26.21 MB
    float*   zp      = ws + off; off += (size_t)4 * B_ * U4_;    //  4.19 MB
    float*   x_emb   = ws + off; off += (size_t)B_ * T_ * 128;   //  1.64 MB
    float*   al_all  = ws + off; off += (size_t)B_ * T_ * 64;    //  0.82 MB
    unsigned* flags  = (unsigned*)(ws + off); off += 1024;       //  4 KB
    bf16_t*  wo_t    = (bf16_t*)(ws + off); off += (size_t)VP_ * 1024 / 2; // 61.6 MB

    // d_out-resident scratch (all dead before the final GEMM writes out):
    float* zemb   = out;                                         // 52.4 MB
    float* hbuf   = zemb + (size_t)3200 * U4_;                   // 13.1 MB
    float* wx_pad = hbuf + (size_t)T_ * HSTR_;                   //  2.1 MB
    float* Wcomb  = wx_pad + (size_t)128 * U4_;                  // 33.6 MB
    float* M2     = Wcomb + (size_t)2048 * U4_;                  // 52.4 MB
    bf16_t* abf   = (bf16_t*)keys;   // post-loop alias (keys dead after loop)

    (void)ws_size;
    (void)hipMemsetAsync(flags, 0, 1024 * sizeof(unsigned), stream);

    // ---- pre-loop ----
    gather_emb_pad<<<B_ * T_, 128, 0, stream>>>(tokens, emb, x_emb);
    pad_wx<<<dim3(U4_ / 256, 128), 256, 0, stream>>>(Wx, bvec, wx_pad);
    // zemb = x_emb_pad @ wx_pad  (bias folded)
    gemm_mfma_split<0><<<dim3(32, 25), 256, 0, stream>>>(
        x_emb, 128, wx_pad, U4_, zemb, U4_, 128);
    // Wcomb = Wa @ Wx[100:1124]  (full 2048 rows)
    gemm_mfma_split<0><<<dim3(32, 16), 256, 0, stream>>>(
        Wa, U_, Wx + (size_t)E_ * U4_, U4_, Wcomb, U4_, U_);
    // Wcomb_top' = Wcomb[0:1024] + Uh
    add_inplace<<<(1024 * U4_) / 256, 256, 0, stream>>>(Wcomb, Uh, 1024 * U4_);
    // M2 = memory_flat @ Wcomb_bot   (3200 x 4096 x 1024)
    gemm_mfma_split<0><<<dim3(32, 25), 256, 0, stream>>>(
        memory, U_, Wcomb + (size_t)1024 * U4_, U4_, M2, U4_, U_);
    // keys = memory @ Wm
    gemm_mfma_split<0><<<dim3(8, 25), 256, 0, stream>>>(
        memory, U_, Wm, U_, keys, U_, U_);
    // t=0 z-partials: zp = h0 @ Uh (4 slices of 256k)
    zgemm_partial<<<dim3(64, 4), 256, 0, stream>>>(h0, U_, Uh, zp);
    // Wo -> transposed bf16
    transpose_wo<<<dim3(VP_ / 64, 1024 / 64), 256, 0, stream>>>(Wo, wo_t);

    // ---- persistent recurrent loop (M2-factored) ----
    decoder_loop13<<<256, 512, 0, stream>>>(
        zemb, Wcomb, M2, keys, memory, c0, hbuf, zp, hc_all, al_all, flags);

    // ---- post-loop ----
    // rebuild ctx half of hc_all from archived align
    ctx_recon<<<B_, 512, 0, stream>>>(al_all, memory, hc_all);
    // abf = bf16(hc_all @ Wa)   (keys region dead; reuse as bf16 buffer)
    gemm_mfma_split<1><<<dim3(8, 25), 256, 0, stream>>>(
        hc_all, 2048, Wa, U_, (float*)abf, U_, 2048);
    // out = abf @ wo_t^T + bo
    gemm_wo_mfma3<<<dim3(VP_ / 128, 25), 256, 0, stream>>>(abf, wo_t, bo, out);
}

// Round 20
// 2244.683 us; speedup vs baseline: 1.1902x; 1.1902x over previous
//
#include <hip/hip_runtime.h>
#include <math.h>

#define B_  64
#define T_  50
#define S_  50
#define U_  1024
#define E_  100
#define V_  30001
#define U4_ 4096
#define VP2_ 30208      // V padded to a multiple of 256 for the 128x256 Wo tile
#define HCSTR_ 131136   // hcbuf plane stride: 64*2048 + 64 pad floats

typedef __bf16 bf16_t;
typedef bf16_t bf16x8 __attribute__((ext_vector_type(8)));
typedef float  f32x4  __attribute__((ext_vector_type(4)));
typedef unsigned long long u64_t;

// ---------------------------------------------------------------------------
// Coherence-point accessors (SYSTEM scope -> sc0+sc1; proven r11-r18).
// ---------------------------------------------------------------------------
__device__ __forceinline__ float2 scload8(const float* p) {
    u64_t v = __hip_atomic_load((const u64_t*)p, __ATOMIC_RELAXED,
                                __HIP_MEMORY_SCOPE_SYSTEM);
    union { u64_t u; float2 f; } c; c.u = v; return c.f;
}
__device__ __forceinline__ void scstore8(float* p, float x, float y) {
    union { u64_t u; float2 f; } c; c.f = make_float2(x, y);
    __hip_atomic_store((u64_t*)p, c.u, __ATOMIC_RELAXED,
                       __HIP_MEMORY_SCOPE_SYSTEM);
}
__device__ __forceinline__ unsigned scload_u(const unsigned* p) {
    return __hip_atomic_load(p, __ATOMIC_RELAXED, __HIP_MEMORY_SCOPE_SYSTEM);
}
__device__ __forceinline__ void scadd_u(unsigned* p) {
    __hip_atomic_fetch_add(p, 1u, __ATOMIC_RELAXED, __HIP_MEMORY_SCOPE_SYSTEM);
}
__device__ __forceinline__ void vm_drain() {
    asm volatile("s_waitcnt vmcnt(0)" ::: "memory");
}
__device__ __forceinline__ void cbar() { asm volatile("" ::: "memory"); }

__global__ void add_inplace(float* __restrict__ dst, const float* __restrict__ src, int n)
{
    int i = blockIdx.x * blockDim.x + threadIdx.x;
    if (i < n) dst[i] += src[i];
}

// x_emb padded to K=128: cols 0..99 = emb[token], col 100 = 1.0, rest 0.
__global__ void gather_emb_pad(const int* __restrict__ tokens,
                               const float* __restrict__ emb,
                               float* __restrict__ xe)
{
    const int r = blockIdx.x;
    const int e = threadIdx.x;
    float v;
    if (e < E_)       v = emb[(size_t)tokens[r] * E_ + e];
    else if (e == E_) v = 1.f;
    else              v = 0.f;
    xe[(size_t)r * 128 + e] = v;
}

// wx_pad[128][4096]: rows 0..99 = Wx top, row 100 = bvec, rows 101..127 = 0.
__global__ void pad_wx(const float* __restrict__ Wx,
                       const float* __restrict__ bvec,
                       float* __restrict__ dst)
{
    const int col = blockIdx.x * 256 + threadIdx.x;
    const int row = blockIdx.y;
    float v;
    if (row < E_)       v = Wx[(size_t)row * U4_ + col];
    else if (row == E_) v = bvec[col];
    else                v = 0.f;
    dst[(size_t)row * U4_ + col] = v;
}

// ---------------------------------------------------------------------------
// Wo [1024][30001] f32 -> wo_t [VP2_][1024] bf16 (transposed, tiled via LDS).
// ---------------------------------------------------------------------------
__global__ __launch_bounds__(256) void transpose_wo(
    const float* __restrict__ wo, bf16_t* __restrict__ dst)
{
    __shared__ bf16_t tile[64][72];
    const int c0 = blockIdx.x * 64;
    const int k0 = blockIdx.y * 64;
    const int tx = threadIdx.x & 63, ty = threadIdx.x >> 6;

#pragma unroll
    for (int kk = ty; kk < 64; kk += 4) {
        const int col = c0 + tx;
        float v = (col < V_) ? wo[(size_t)(k0 + kk) * V_ + col] : 0.f;
        tile[kk][tx] = (bf16_t)v;
    }
    __syncthreads();
#pragma unroll
    for (int cc = ty; cc < 64; cc += 4)
        dst[(size_t)(c0 + cc) * 1024 + k0 + tx] = tile[tx][cc];
}

// ---------------------------------------------------------------------------
// Split-bf16 3-pass MFMA GEMM (r15-proven): C = A@B, rel err ~2^-18.
// ---------------------------------------------------------------------------
template <int OUT>
__global__ __launch_bounds__(256) void gemm_mfma_split(
    const float* __restrict__ A, int lda,
    const float* __restrict__ Bm, int ldb,
    float* __restrict__ C, int ldc, int K)
{
    __shared__ bf16_t As_h[128][40];
    __shared__ bf16_t As_l[128][40];
    __shared__ bf16_t Bs_h[128][40];
    __shared__ bf16_t Bs_l[128][40];

    const int n0  = blockIdx.x * 128;
    const int m0  = blockIdx.y * 128;
    const int tid = threadIdx.x;
    const int wave = tid >> 6, lane = tid & 63;
    const int wr = wave >> 1, wc = wave & 1;
    const int lr = lane & 15;
    const int lk = lane >> 4;

    f32x4 acc[4][4] = {};

    const int ar  = tid >> 1, ak = (tid & 1) * 16;
    const int bk0 = (tid >> 5) * 4, bc = (tid & 31) * 4;

    for (int k0 = 0; k0 < K; k0 += 32) {
        {
            const float* ap = &A[(size_t)(m0 + ar) * lda + k0 + ak];
            bf16x8 h0v, l0v, h1v, l1v;
#pragma unroll
            for (int q = 0; q < 2; ++q) {
                float4 v0 = *(const float4*)&ap[q * 8];
                float4 v1 = *(const float4*)&ap[q * 8 + 4];
                float xs[8] = {v0.x, v0.y, v0.z, v0.w, v1.x, v1.y, v1.z, v1.w};
#pragma unroll
                for (int e = 0; e < 8; ++e) {
                    bf16_t h = (bf16_t)xs[e];
                    if (q == 0) { h0v[e] = h; l0v[e] = (bf16_t)(xs[e] - (float)h); }
                    else        { h1v[e] = h; l1v[e] = (bf16_t)(xs[e] - (float)h); }
                }
            }
            *(bf16x8*)&As_h[ar][ak]     = h0v;
            *(bf16x8*)&As_h[ar][ak + 8] = h1v;
            *(bf16x8*)&As_l[ar][ak]     = l0v;
            *(bf16x8*)&As_l[ar][ak + 8] = l1v;
        }
        {
#pragma unroll
            for (int kk = 0; kk < 4; ++kk) {
                float4 v = *(const float4*)&Bm[(size_t)(k0 + bk0 + kk) * ldb + n0 + bc];
                float xs[4] = {v.x, v.y, v.z, v.w};
#pragma unroll
                for (int i = 0; i < 4; ++i) {
                    bf16_t h = (bf16_t)xs[i];
                    Bs_h[bc + i][bk0 + kk] = h;
                    Bs_l[bc + i][bk0 + kk] = (bf16_t)(xs[i] - (float)h);
                }
            }
        }
        __syncthreads();

        bf16x8 ah[4], alv[4], bh[4], bl[4];
#pragma unroll
        for (int m = 0; m < 4; ++m) {
            ah[m]  = *(const bf16x8*)&As_h[wr * 64 + m * 16 + lr][lk * 8];
            alv[m] = *(const bf16x8*)&As_l[wr * 64 + m * 16 + lr][lk * 8];
        }
#pragma unroll
        for (int n = 0; n < 4; ++n) {
            bh[n] = *(const bf16x8*)&Bs_h[wc * 64 + n * 16 + lr][lk * 8];
            bl[n] = *(const bf16x8*)&Bs_l[wc * 64 + n * 16 + lr][lk * 8];
        }
#pragma unroll
        for (int m = 0; m < 4; ++m)
#pragma unroll
            for (int n = 0; n < 4; ++n) {
                acc[m][n] = __builtin_amdgcn_mfma_f32_16x16x32_bf16(ah[m],  bh[n], acc[m][n], 0, 0, 0);
                acc[m][n] = __builtin_amdgcn_mfma_f32_16x16x32_bf16(ah[m],  bl[n], acc[m][n], 0, 0, 0);
                acc[m][n] = __builtin_amdgcn_mfma_f32_16x16x32_bf16(alv[m], bh[n], acc[m][n], 0, 0, 0);
            }
        __syncthreads();
    }

#pragma unroll
    for (int m = 0; m < 4; ++m) {
        const int row = m0 + wr * 64 + m * 16 + lk * 4;
#pragma unroll
        for (int n = 0; n < 4; ++n) {
            const int col = n0 + wc * 64 + n * 16 + lr;
#pragma unroll
            for (int r = 0; r < 4; ++r) {
                if (OUT == 0)
                    C[(size_t)(row + r) * ldc + col] = acc[m][n][r];
                else
                    ((bf16_t*)C)[(size_t)(row + r) * ldc + col] = (bf16_t)acc[m][n][r];
            }
        }
    }
}

// ---------------------------------------------------------------------------
// Split-K GEMM for t=0: zp[(ks*64+b)*4096+n] = sum_{k in 256-slice} h0@Uh.
// ---------------------------------------------------------------------------
__global__ __launch_bounds__(256) void zgemm_partial(
    const float* __restrict__ A, int lda,
    const float* __restrict__ Bm,
    float* __restrict__ zp)
{
    __shared__ float As[64][17];
    __shared__ float Bs[16][68];

    const int n0     = blockIdx.x * 64;
    const int ks     = blockIdx.y;
    const int k_base = ks * 256;
    const int tid    = threadIdx.x;
    const int tx     = tid & 15, ty = tid >> 4;

    float acc[4][4];
#pragma unroll
    for (int i = 0; i < 4; ++i)
#pragma unroll
        for (int j = 0; j < 4; ++j) acc[i][j] = 0.f;

    const int ra = tid >> 2, ca = (tid & 3) * 4;
    const int rb = tid >> 4, cb = (tid & 15) * 4;

    for (int kt = 0; kt < 16; ++kt) {
        const int k0 = k_base + kt * 16;
        float4 av = *(const float4*)&A[(size_t)ra * lda + k0 + ca];
        As[ra][ca + 0] = av.x;
        As[ra][ca + 1] = av.y;
        As[ra][ca + 2] = av.z;
        As[ra][ca + 3] = av.w;
        float4 bv = *(const float4*)&Bm[(size_t)(k0 + rb) * U4_ + n0 + cb];
        *(float4*)&Bs[rb][cb] = bv;
        __syncthreads();
#pragma unroll
        for (int kk = 0; kk < 16; ++kk) {
            float a_[4];
#pragma unroll
            for (int i = 0; i < 4; ++i) a_[i] = As[ty * 4 + i][kk];
            float4 bq = *(const float4*)&Bs[kk][tx * 4];
            float b_[4] = {bq.x, bq.y, bq.z, bq.w};
#pragma unroll
            for (int i = 0; i < 4; ++i)
#pragma unroll
                for (int j = 0; j < 4; ++j)
                    acc[i][j] = fmaf(a_[i], b_[j], acc[i][j]);
        }
        __syncthreads();
    }

#pragma unroll
    for (int i = 0; i < 4; ++i)
        *(float4*)&zp[((size_t)ks * 64 + ty * 4 + i) * U4_ + n0 + tx * 4] =
            make_float4(acc[i][0], acc[i][1], acc[i][2], acc[i][3]);
}

// ---------------------------------------------------------------------------
// Persistent decoder loop v11 (r17, best known — byte-identical revert).
// ---------------------------------------------------------------------------
__global__ __launch_bounds__(512) void decoder_loop11(
    const float* __restrict__ zemb,   // [3200][4096] (in d_out)
    const float* __restrict__ Wcomb,  // [2048][4096]
    const float* __restrict__ keys,   // [64][50][1024]
    const float* __restrict__ memory, // [64][50][1024]
    const float* __restrict__ c0,
    float* __restrict__ hcbuf,        // [50][HCSTR_] (in d_out)
    float* __restrict__ zp,           // [4][64][4096] (sc-ops only)
    float* __restrict__ hc_all,       // [64][50][2048] (plain)
    unsigned* flags)
{
    static __shared__ __attribute__((aligned(16))) char smem[153088];
    bf16_t* wfr = (bf16_t*)smem;                    // 131072 B frag store
    float*  tr  = (float*)(smem + 131072);          // [64][68] transpose
    float*  hs  = (float*)(smem + 148480);          // 1024
    float*  sc  = (float*)(smem + 152576);          // 64
    float*  al  = (float*)(smem + 152832);          // 64

    const int beta = blockIdx.x;
    const int tid  = threadIdx.x;

    const int nt = beta & 63, ks = beta >> 6;
    const int koff = ks * 512;
    const int c0c  = nt * 64;

    // ---- pack Wcomb slice [512 k][64 cols] -> LDS fragments (once) ----
    for (int i = tid; i < 512 * 64; i += 512) {
        const int k = i >> 6, col = i & 63;
        const float w = Wcomb[(size_t)(koff + k) * U4_ + c0c + col];
        const bf16_t hi = (bf16_t)w;
        const bf16_t lo = (bf16_t)(w - (float)hi);
        const int ntile = col >> 4, lane_lo = col & 15;
        const int kk = k >> 5, kr = k & 31;
        const int lane = (kr >> 3) * 16 + lane_lo, j = kr & 7;
        const int base = ((ntile * 16 + kk) * 2) * 512 + lane * 8 + j;
        wfr[base]       = hi;
        wfr[base + 512] = lo;
    }

    const int b  = beta;
    const int u2 = tid * 2;
    float creg[2] = {0.f, 0.f};
    if (beta < 64) {
        float2 cv = *(const float2*)&c0[b * U_ + u2];
        creg[0] = cv.x;
        creg[1] = cv.y;
    }
    __syncthreads();

    const int w  = tid >> 6, l = tid & 63;
    const int mt = w >> 1, ntb = (w & 1) * 2;
    const int arow = mt * 16 + (l & 15);
    const int aq   = l >> 4;
    const size_t abase = (size_t)arow * 2048 + koff + aq * 8;

    for (int t = 0; t < T_; ++t) {
        // ---------------- phase A (t>=1): zp = hcbuf[t-1] @ Wcomb (MFMA) ----
        if (t) {
            {   // wait on producer of my k-half
                const unsigned tgt = 8u * (unsigned)t;
                const unsigned* fb = (ks < 2) ? &flags[512] : &flags[768];
                if (tid < 8) {
                    const unsigned* f = fb + tid * 32;
                    while (scload_u(f) < tgt) __builtin_amdgcn_s_sleep(1);
                }
                __syncthreads();
                cbar();
            }

            const float* ap = &hcbuf[(size_t)(t - 1) * HCSTR_ + abase];

            f32x4 acc[2] = {};
            float4 ca0 = *(const float4*)&ap[0];
            float4 ca1 = *(const float4*)&ap[4];
#pragma unroll
            for (int kk = 0; kk < 16; ++kk) {
                float4 pa0, pa1;
                if (kk < 15) {
                    pa0 = *(const float4*)&ap[(kk + 1) * 32];
                    pa1 = *(const float4*)&ap[(kk + 1) * 32 + 4];
                }
                float xs[8] = {ca0.x, ca0.y, ca0.z, ca0.w,
                               ca1.x, ca1.y, ca1.z, ca1.w};
                bf16x8 ah, alv;
#pragma unroll
                for (int e = 0; e < 8; ++e) {
                    bf16_t h = (bf16_t)xs[e];
                    ah[e]  = h;
                    alv[e] = (bf16_t)(xs[e] - (float)h);
                }
#pragma unroll
                for (int nn = 0; nn < 2; ++nn) {
                    const int fb2 = (((ntb + nn) * 16 + kk) * 2) * 512 + l * 8;
                    bf16x8 bh = *(const bf16x8*)&wfr[fb2];
                    bf16x8 bl = *(const bf16x8*)&wfr[fb2 + 512];
                    acc[nn] = __builtin_amdgcn_mfma_f32_16x16x32_bf16(ah, bh, acc[nn], 0, 0, 0);
                    acc[nn] = __builtin_amdgcn_mfma_f32_16x16x32_bf16(ah, bl, acc[nn], 0, 0, 0);
                    acc[nn] = __builtin_amdgcn_mfma_f32_16x16x32_bf16(alv, bh, acc[nn], 0, 0, 0);
                }
                ca0 = pa0;
                ca1 = pa1;
            }

#pragma unroll
            for (int nn = 0; nn < 2; ++nn)
#pragma unroll
                for (int rr = 0; rr < 4; ++rr)
                    tr[(mt * 16 + (l >> 4) * 4 + rr) * 68 + (ntb + nn) * 16 + (l & 15)] =
                        acc[nn][rr];
            __syncthreads();

            {
                const int zb = tid >> 3, cg = (tid & 7) * 8;
                float4 r0 = *(const float4*)&tr[zb * 68 + cg];
                float4 r1 = *(const float4*)&tr[zb * 68 + cg + 4];
                float* zrow = &zp[((size_t)(ks * 64 + zb)) * U4_ + c0c + cg];
                scstore8(zrow + 0, r0.x, r0.y);
                scstore8(zrow + 2, r0.z, r0.w);
                scstore8(zrow + 4, r1.x, r1.y);
                scstore8(zrow + 6, r1.z, r1.w);
            }
            vm_drain();
            __syncthreads();
            if (tid == 0) scadd_u(&flags[(beta & 15) * 32]);   // zp group flag
        }

        // ---------------- phase BC: gates + attention (blocks < 64) ---------
        if (beta < 64) {
            if (t) {
                const unsigned tgt = 16u * (unsigned)t;
                if (tid < 16) {
                    const unsigned* f = &flags[tid * 32];
                    while (scload_u(f) < tgt) __builtin_amdgcn_s_sleep(1);
                }
                __syncthreads();
                cbar();
            }

            const float* ze = &zemb[((size_t)b * T_ + t) * U4_];
            float zgx[4], zgy[4];
#pragma unroll
            for (int g = 0; g < 4; ++g) {
                float2 a = *(const float2*)&ze[g * U_ + u2];
                zgx[g] = a.x;
                zgy[g] = a.y;
            }
#pragma unroll
            for (int s = 0; s < 4; ++s) {
#pragma unroll
                for (int g = 0; g < 4; ++g) {
                    float2 v = scload8(&zp[((size_t)s * 64 + b) * U4_ + g * U_ + u2]);
                    zgx[g] += v.x;
                    zgy[g] += v.y;
                }
            }

            const float six = 1.f / (1.f + expf(-zgx[0]));
            const float sfx = 1.f / (1.f + expf(-zgx[1]));
            const float tgx = tanhf(zgx[2]);
            const float sox = 1.f / (1.f + expf(-zgx[3]));
            const float cnx = sfx * creg[0] + six * tgx;
            creg[0] = cnx;
            const float hnx = sox * tanhf(cnx);

            const float siy = 1.f / (1.f + expf(-zgy[0]));
            const float sfy = 1.f / (1.f + expf(-zgy[1]));
            const float tgy = tanhf(zgy[2]);
            const float soy = 1.f / (1.f + expf(-zgy[3]));
            const float cny = sfy * creg[1] + siy * tgy;
            creg[1] = cny;
            const float hny = soy * tanhf(cny);

            float* hcb_t = &hcbuf[(size_t)t * HCSTR_];
            hs[u2]     = hnx;
            hs[u2 + 1] = hny;
            scstore8(&hcb_t[b * 2048 + u2], hnx, hny);
            *(float2*)&hc_all[((size_t)b * T_ + t) * 2048 + u2] =
                make_float2(hnx, hny);
            vm_drain();
            __syncthreads();
            if (tid == 0) scadd_u(&flags[512 + (b & 7) * 32]);  // h group flag

            const int lane = tid & 63, wv = tid >> 6;
            for (int s = wv; s < S_; s += 8) {
                const float* kp = &keys[((size_t)b * S_ + s) * U_ + lane * 16];
                const float* hp = &hs[lane * 16];
                float p = 0.f;
#pragma unroll
                for (int q = 0; q < 4; ++q) {
                    float4 kv = *(const float4*)&kp[q * 4];
                    float4 hv = *(const float4*)&hp[q * 4];
                    p = fmaf(hv.x, kv.x, p);
                    p = fmaf(hv.y, kv.y, p);
                    p = fmaf(hv.z, kv.z, p);
                    p = fmaf(hv.w, kv.w, p);
                }
#pragma unroll
                for (int off = 32; off > 0; off >>= 1)
                    p += __shfl_xor(p, off);
                if (lane == 0) sc[s] = p;
            }
            __syncthreads();

            if (tid < 64) {
                float v = (tid < S_) ? sc[tid] : -INFINITY;
                float m = v;
#pragma unroll
                for (int off = 32; off > 0; off >>= 1)
                    m = fmaxf(m, __shfl_xor(m, off));
                float e = (tid < S_) ? expf(v - m) : 0.f;
                float ssum = e;
#pragma unroll
                for (int off = 32; off > 0; off >>= 1)
                    ssum += __shfl_xor(ssum, off);
                if (tid < S_) al[tid] = e / ssum;
            }
            __syncthreads();

            {
                const float2* mp = (const float2*)&memory[(size_t)b * S_ * U_];
                float cx = 0.f, cy = 0.f;
#pragma unroll 10
                for (int s = 0; s < S_; ++s) {
                    float2 mv = mp[s * 512 + tid];
                    const float a = al[s];
                    cx = fmaf(a, mv.x, cx);
                    cy = fmaf(a, mv.y, cy);
                }
                scstore8(&hcb_t[b * 2048 + U_ + u2], cx, cy);
                *(float2*)&hc_all[((size_t)b * T_ + t) * 2048 + U_ + u2] =
                    make_float2(cx, cy);
            }
            vm_drain();
            __syncthreads();
            if (tid == 0) scadd_u(&flags[768 + (b & 7) * 32]);  // ctx group flag
        }
    }
}

// ---------------------------------------------------------------------------
// bf16 MFMA GEMM for Wo, 128x256 tile, double-buffered:
// C = A[3200][1024] @ Bt^T + bias, Bt[VP2_][1024].
// 4 waves: wr = wave>>1 (m-half of 64), wc = wave&1 (n-half of 128).
// LDS 60 KB -> 2 blocks/CU. A-traffic halved vs 128x128.
// ---------------------------------------------------------------------------
__global__ __launch_bounds__(256) void gemm_wo_mfma4(
    const bf16_t* __restrict__ A,    // [3200][1024]
    const bf16_t* __restrict__ Bt,   // [VP2_][1024]
    const float*  __restrict__ bias, // [V_]
    float* __restrict__ C)           // [3200][V_]
{
    __shared__ bf16_t As[2][128][40];
    __shared__ bf16_t Bs[2][256][40];

    const int n0  = blockIdx.x * 256;
    const int m0  = blockIdx.y * 128;
    const int tid = threadIdx.x;
    const int wave = tid >> 6, lane = tid & 63;
    const int wr = wave >> 1, wc = wave & 1;
    const int lr = lane & 15;
    const int lk = lane >> 4;

    f32x4 acc[4][8] = {};

    const int ar = tid >> 1, ak = (tid & 1) * 16;   // A: 128 rows x 32 k
    const int br = tid;                              // B: 256 rows x 32 k
    const bf16_t* apb = &A[(size_t)(m0 + ar) * U_ + ak];
    const bf16_t* bpb = &Bt[(size_t)(n0 + br) * U_];

    // prologue: stage k0=0 into buffer 0
    {
        *(bf16x8*)&As[0][ar][ak]     = *(const bf16x8*)&apb[0];
        *(bf16x8*)&As[0][ar][ak + 8] = *(const bf16x8*)&apb[8];
        *(bf16x8*)&Bs[0][br][0]      = *(const bf16x8*)&bpb[0];
        *(bf16x8*)&Bs[0][br][8]      = *(const bf16x8*)&bpb[8];
        *(bf16x8*)&Bs[0][br][16]     = *(const bf16x8*)&bpb[16];
        *(bf16x8*)&Bs[0][br][24]     = *(const bf16x8*)&bpb[24];
    }
    __syncthreads();

    for (int k0 = 0; k0 < U_; k0 += 32) {
        const int cur = (k0 >> 5) & 1;
        bf16x8 na0, na1, nb0, nb1, nb2, nb3;
        const bool more = (k0 + 32 < U_);
        if (more) {
            na0 = *(const bf16x8*)&apb[k0 + 32];
            na1 = *(const bf16x8*)&apb[k0 + 40];
            nb0 = *(const bf16x8*)&bpb[k0 + 32];
            nb1 = *(const bf16x8*)&bpb[k0 + 40];
            nb2 = *(const bf16x8*)&bpb[k0 + 48];
            nb3 = *(const bf16x8*)&bpb[k0 + 56];
        }

        bf16x8 af[4], bf[8];
#pragma unroll
        for (int m = 0; m < 4; ++m)
            af[m] = *(const bf16x8*)&As[cur][wr * 64 + m * 16 + lr][lk * 8];
#pragma unroll
        for (int n = 0; n < 8; ++n)
            bf[n] = *(const bf16x8*)&Bs[cur][wc * 128 + n * 16 + lr][lk * 8];
#pragma unroll
        for (int m = 0; m < 4; ++m)
#pragma unroll
            for (int n = 0; n < 8; ++n)
                acc[m][n] = __builtin_amdgcn_mfma_f32_16x16x32_bf16(
                    af[m], bf[n], acc[m][n], 0, 0, 0);

        if (more) {
            *(bf16x8*)&As[cur ^ 1][ar][ak]     = na0;
            *(bf16x8*)&As[cur ^ 1][ar][ak + 8] = na1;
            *(bf16x8*)&Bs[cur ^ 1][br][0]      = nb0;
            *(bf16x8*)&Bs[cur ^ 1][br][8]      = nb1;
            *(bf16x8*)&Bs[cur ^ 1][br][16]     = nb2;
            *(bf16x8*)&Bs[cur ^ 1][br][24]     = nb3;
        }
        __syncthreads();
    }

#pragma unroll
    for (int m = 0; m < 4; ++m) {
        const int row = m0 + wr * 64 + m * 16 + lk * 4;
#pragma unroll
        for (int n = 0; n < 8; ++n) {
            const int col = n0 + wc * 128 + n * 16 + lr;
            if (col < V_) {
                const float bb = bias[col];
#pragma unroll
                for (int r = 0; r < 4; ++r)
                    C[(size_t)(row + r) * V_ + col] = acc[m][n][r] + bb;
            }
        }
    }
}

// ---------------------------------------------------------------------------
extern "C" void kernel_launch(void* const* d_in, const int* in_sizes, int n_in,
                              void* d_out, int out_size, void* d_ws, size_t ws_size,
                              hipStream_t stream)
{
    const int*   tokens = (const int*)  d_in[0];
    const float* memory = (const float*)d_in[1];
    const float* h0     = (const float*)d_in[2];
    const float* c0     = (const float*)d_in[3];
    const float* emb    = (const float*)d_in[4];
    const float* Wx     = (const float*)d_in[5];
    const float* Uh     = (const float*)d_in[6];
    const float* bvec   = (const float*)d_in[7];
    const float* Wm     = (const float*)d_in[8];
    const float* Wa     = (const float*)d_in[9];
    const float* Wo     = (const float*)d_in[10];
    const float* bo     = (const float*)d_in[11];
    float* out = (float*)d_out;

    // ---- workspace layout (float units) ----
    float* ws = (float*)d_ws;
    size_t off = 0;
    float*   Wcomb  = ws + off; off += (size_t)2048 * U4_;      // 33.55 MB
    float*   keys   = ws + off; off += (size_t)B_ * S_ * U_;    // 13.11 MB
    float*   hc_all = ws + off; off += (size_t)B_ * T_ * 2048;  // 26.21 MB
    float*   zp     = ws + off; off += (size_t)4 * B_ * U4_;    //  4.19 MB
    float*   x_emb  = ws + off; off += (size_t)B_ * T_ * 128;   //  1.64 MB
    unsigned* flags = (unsigned*)(ws + off); off += 1024;       //  4 KB
    bf16_t*  wo_t   = (bf16_t*)(ws + off); off += (size_t)VP2_ * 1024 / 2; // 61.9 MB

    // d_out-resident scratch (all dead before the final GEMM writes out):
    float* zemb   = out;                               // [3200][4096]  52.4 MB
    float* hcbuf  = out + (size_t)3200 * U4_;          // [50][HCSTR_]  26.2 MB
    float* wx_pad = out + (size_t)3200 * U4_ + (size_t)T_ * HCSTR_; // [128][4096]
    bf16_t* abf   = (bf16_t*)Wcomb;                    // post-loop alias

    (void)ws_size;
    (void)hipMemsetAsync(flags, 0, 1024 * sizeof(unsigned), stream);

    // ---- pre-loop ----
    gather_emb_pad<<<B_ * T_, 128, 0, stream>>>(tokens, emb, x_emb);
    pad_wx<<<dim3(U4_ / 256, 128), 256, 0, stream>>>(Wx, bvec, wx_pad);
    gemm_mfma_split<0><<<dim3(32, 25), 256, 0, stream>>>(
        x_emb, 128, wx_pad, U4_, zemb, U4_, 128);
    gemm_mfma_split<0><<<dim3(32, 16), 256, 0, stream>>>(
        Wa, U_, Wx + (size_t)E_ * U4_, U4_, Wcomb, U4_, U_);
    add_inplace<<<(1024 * U4_) / 256, 256, 0, stream>>>(Wcomb, Uh, 1024 * U4_);
    gemm_mfma_split<0><<<dim3(8, 25), 256, 0, stream>>>(
        memory, U_, Wm, U_, keys, U_, U_);
    zgemm_partial<<<dim3(64, 4), 256, 0, stream>>>(h0, U_, Uh, zp);
    transpose_wo<<<dim3(VP2_ / 64, 1024 / 64), 256, 0, stream>>>(Wo, wo_t);

    // ---- persistent recurrent loop (r17 best-known) ----
    decoder_loop11<<<256, 512, 0, stream>>>(
        zemb, Wcomb, keys, memory, c0, hcbuf, zp, hc_all, flags);

    // ---- post-loop ----
    gemm_mfma_split<1><<<dim3(8, 25), 256, 0, stream>>>(
        hc_all, 2048, Wa, U_, (float*)abf, U_, 2048);
    gemm_wo_mfma4<<<dim3(VP2_ / 256, 25), 256, 0, stream>>>(abf, wo_t, bo, out);
}

// Round 21
// 2137.725 us; speedup vs baseline: 1.2497x; 1.0500x over previous
//
#include <hip/hip_runtime.h>
#include <math.h>

#define B_  64
#define T_  50
#define S_  50
#define U_  1024
#define E_  100
#define V_  30001
#define U4_ 4096
#define VP_ 30080       // V padded to a multiple of 128 for bf16 staging
#define HCSTR_ 131136   // hcbuf plane stride: 64*2048 + 64 pad floats

typedef __bf16 bf16_t;
typedef bf16_t bf16x8 __attribute__((ext_vector_type(8)));
typedef float  f32x4  __attribute__((ext_vector_type(4)));
typedef unsigned long long u64_t;

// ---------------------------------------------------------------------------
// Coherence-point accessors (SYSTEM scope -> sc0+sc1; proven r11-r17).
// ---------------------------------------------------------------------------
__device__ __forceinline__ float2 scload8(const float* p) {
    u64_t v = __hip_atomic_load((const u64_t*)p, __ATOMIC_RELAXED,
                                __HIP_MEMORY_SCOPE_SYSTEM);
    union { u64_t u; float2 f; } c; c.u = v; return c.f;
}
__device__ __forceinline__ void scstore8(float* p, float x, float y) {
    union { u64_t u; float2 f; } c; c.f = make_float2(x, y);
    __hip_atomic_store((u64_t*)p, c.u, __ATOMIC_RELAXED,
                       __HIP_MEMORY_SCOPE_SYSTEM);
}
__device__ __forceinline__ unsigned scload_u(const unsigned* p) {
    return __hip_atomic_load(p, __ATOMIC_RELAXED, __HIP_MEMORY_SCOPE_SYSTEM);
}
__device__ __forceinline__ void scadd_u(unsigned* p) {
    __hip_atomic_fetch_add(p, 1u, __ATOMIC_RELAXED, __HIP_MEMORY_SCOPE_SYSTEM);
}
__device__ __forceinline__ void vm_drain() {
    asm volatile("s_waitcnt vmcnt(0)" ::: "memory");
}
__device__ __forceinline__ void cbar() { asm volatile("" ::: "memory"); }

__global__ void add_inplace(float* __restrict__ dst, const float* __restrict__ src, int n)
{
    int i = blockIdx.x * blockDim.x + threadIdx.x;
    if (i < n) dst[i] += src[i];
}

// x_emb padded to K=128: cols 0..99 = emb[token], col 100 = 1.0, rest 0.
__global__ void gather_emb_pad(const int* __restrict__ tokens,
                               const float* __restrict__ emb,
                               float* __restrict__ xe)
{
    const int r = blockIdx.x;
    const int e = threadIdx.x;
    float v;
    if (e < E_)       v = emb[(size_t)tokens[r] * E_ + e];
    else if (e == E_) v = 1.f;
    else              v = 0.f;
    xe[(size_t)r * 128 + e] = v;
}

// wx_pad[128][4096]: rows 0..99 = Wx top, row 100 = bvec, rows 101..127 = 0.
__global__ void pad_wx(const float* __restrict__ Wx,
                       const float* __restrict__ bvec,
                       float* __restrict__ dst)
{
    const int col = blockIdx.x * 256 + threadIdx.x;
    const int row = blockIdx.y;
    float v;
    if (row < E_)       v = Wx[(size_t)row * U4_ + col];
    else if (row == E_) v = bvec[col];
    else                v = 0.f;
    dst[(size_t)row * U4_ + col] = v;
}

// ---------------------------------------------------------------------------
// Wo [1024][30001] f32 -> wo_t [VP_][1024] bf16 (transposed, tiled via LDS).
// ---------------------------------------------------------------------------
__global__ __launch_bounds__(256) void transpose_wo(
    const float* __restrict__ wo, bf16_t* __restrict__ dst)
{
    __shared__ bf16_t tile[64][72];
    const int c0 = blockIdx.x * 64;
    const int k0 = blockIdx.y * 64;
    const int tx = threadIdx.x & 63, ty = threadIdx.x >> 6;

#pragma unroll
    for (int kk = ty; kk < 64; kk += 4) {
        const int col = c0 + tx;
        float v = (col < V_) ? wo[(size_t)(k0 + kk) * V_ + col] : 0.f;
        tile[kk][tx] = (bf16_t)v;
    }
    __syncthreads();
#pragma unroll
    for (int cc = ty; cc < 64; cc += 4)
        dst[(size_t)(c0 + cc) * 1024 + k0 + tx] = tile[tx][cc];
}

// ---------------------------------------------------------------------------
// Split-bf16 3-pass MFMA GEMM (r15-proven): C = A@B, rel err ~2^-18.
// ---------------------------------------------------------------------------
template <int OUT>
__global__ __launch_bounds__(256) void gemm_mfma_split(
    const float* __restrict__ A, int lda,
    const float* __restrict__ Bm, int ldb,
    float* __restrict__ C, int ldc, int K)
{
    __shared__ bf16_t As_h[128][40];
    __shared__ bf16_t As_l[128][40];
    __shared__ bf16_t Bs_h[128][40];
    __shared__ bf16_t Bs_l[128][40];

    const int n0  = blockIdx.x * 128;
    const int m0  = blockIdx.y * 128;
    const int tid = threadIdx.x;
    const int wave = tid >> 6, lane = tid & 63;
    const int wr = wave >> 1, wc = wave & 1;
    const int lr = lane & 15;
    const int lk = lane >> 4;

    f32x4 acc[4][4] = {};

    const int ar  = tid >> 1, ak = (tid & 1) * 16;
    const int bk0 = (tid >> 5) * 4, bc = (tid & 31) * 4;

    for (int k0 = 0; k0 < K; k0 += 32) {
        {
            const float* ap = &A[(size_t)(m0 + ar) * lda + k0 + ak];
            bf16x8 h0v, l0v, h1v, l1v;
#pragma unroll
            for (int q = 0; q < 2; ++q) {
                float4 v0 = *(const float4*)&ap[q * 8];
                float4 v1 = *(const float4*)&ap[q * 8 + 4];
                float xs[8] = {v0.x, v0.y, v0.z, v0.w, v1.x, v1.y, v1.z, v1.w};
#pragma unroll
                for (int e = 0; e < 8; ++e) {
                    bf16_t h = (bf16_t)xs[e];
                    if (q == 0) { h0v[e] = h; l0v[e] = (bf16_t)(xs[e] - (float)h); }
                    else        { h1v[e] = h; l1v[e] = (bf16_t)(xs[e] - (float)h); }
                }
            }
            *(bf16x8*)&As_h[ar][ak]     = h0v;
            *(bf16x8*)&As_h[ar][ak + 8] = h1v;
            *(bf16x8*)&As_l[ar][ak]     = l0v;
            *(bf16x8*)&As_l[ar][ak + 8] = l1v;
        }
        {
#pragma unroll
            for (int kk = 0; kk < 4; ++kk) {
                float4 v = *(const float4*)&Bm[(size_t)(k0 + bk0 + kk) * ldb + n0 + bc];
                float xs[4] = {v.x, v.y, v.z, v.w};
#pragma unroll
                for (int i = 0; i < 4; ++i) {
                    bf16_t h = (bf16_t)xs[i];
                    Bs_h[bc + i][bk0 + kk] = h;
                    Bs_l[bc + i][bk0 + kk] = (bf16_t)(xs[i] - (float)h);
                }
            }
        }
        __syncthreads();

        bf16x8 ah[4], alv[4], bh[4], bl[4];
#pragma unroll
        for (int m = 0; m < 4; ++m) {
            ah[m]  = *(const bf16x8*)&As_h[wr * 64 + m * 16 + lr][lk * 8];
            alv[m] = *(const bf16x8*)&As_l[wr * 64 + m * 16 + lr][lk * 8];
        }
#pragma unroll
        for (int n = 0; n < 4; ++n) {
            bh[n] = *(const bf16x8*)&Bs_h[wc * 64 + n * 16 + lr][lk * 8];
            bl[n] = *(const bf16x8*)&Bs_l[wc * 64 + n * 16 + lr][lk * 8];
        }
#pragma unroll
        for (int m = 0; m < 4; ++m)
#pragma unroll
            for (int n = 0; n < 4; ++n) {
                acc[m][n] = __builtin_amdgcn_mfma_f32_16x16x32_bf16(ah[m],  bh[n], acc[m][n], 0, 0, 0);
                acc[m][n] = __builtin_amdgcn_mfma_f32_16x16x32_bf16(ah[m],  bl[n], acc[m][n], 0, 0, 0);
                acc[m][n] = __builtin_amdgcn_mfma_f32_16x16x32_bf16(alv[m], bh[n], acc[m][n], 0, 0, 0);
            }
        __syncthreads();
    }

#pragma unroll
    for (int m = 0; m < 4; ++m) {
        const int row = m0 + wr * 64 + m * 16 + lk * 4;
#pragma unroll
        for (int n = 0; n < 4; ++n) {
            const int col = n0 + wc * 64 + n * 16 + lr;
#pragma unroll
            for (int r = 0; r < 4; ++r) {
                if (OUT == 0)
                    C[(size_t)(row + r) * ldc + col] = acc[m][n][r];
                else
                    ((bf16_t*)C)[(size_t)(row + r) * ldc + col] = (bf16_t)acc[m][n][r];
            }
        }
    }
}

// ---------------------------------------------------------------------------
// Split-K GEMM for t=0: zp[(ks*64+b)*4096+n] = sum_{k in 256-slice} h0@Uh.
// ---------------------------------------------------------------------------
__global__ __launch_bounds__(256) void zgemm_partial(
    const float* __restrict__ A, int lda,
    const float* __restrict__ Bm,
    float* __restrict__ zp)
{
    __shared__ float As[64][17];
    __shared__ float Bs[16][68];

    const int n0     = blockIdx.x * 64;
    const int ks     = blockIdx.y;
    const int k_base = ks * 256;
    const int tid    = threadIdx.x;
    const int tx     = tid & 15, ty = tid >> 4;

    float acc[4][4];
#pragma unroll
    for (int i = 0; i < 4; ++i)
#pragma unroll
        for (int j = 0; j < 4; ++j) acc[i][j] = 0.f;

    const int ra = tid >> 2, ca = (tid & 3) * 4;
    const int rb = tid >> 4, cb = (tid & 15) * 4;

    for (int kt = 0; kt < 16; ++kt) {
        const int k0 = k_base + kt * 16;
        float4 av = *(const float4*)&A[(size_t)ra * lda + k0 + ca];
        As[ra][ca + 0] = av.x;
        As[ra][ca + 1] = av.y;
        As[ra][ca + 2] = av.z;
        As[ra][ca + 3] = av.w;
        float4 bv = *(const float4*)&Bm[(size_t)(k0 + rb) * U4_ + n0 + cb];
        *(float4*)&Bs[rb][cb] = bv;
        __syncthreads();
#pragma unroll
        for (int kk = 0; kk < 16; ++kk) {
            float a_[4];
#pragma unroll
            for (int i = 0; i < 4; ++i) a_[i] = As[ty * 4 + i][kk];
            float4 bq = *(const float4*)&Bs[kk][tx * 4];
            float b_[4] = {bq.x, bq.y, bq.z, bq.w};
#pragma unroll
            for (int i = 0; i < 4; ++i)
#pragma unroll
                for (int j = 0; j < 4; ++j)
                    acc[i][j] = fmaf(a_[i], b_[j], acc[i][j]);
        }
        __syncthreads();
    }

#pragma unroll
    for (int i = 0; i < 4; ++i)
        *(float4*)&zp[((size_t)ks * 64 + ty * 4 + i) * U4_ + n0 + tx * 4] =
            make_float4(acc[i][0], acc[i][1], acc[i][2], acc[i][3]);
}

// ---------------------------------------------------------------------------
// Persistent decoder loop v11 (r17, best known): phase A MFMA with
// direct-from-global A fragments, hcbuf rotation, tree'd flags, fenceless
// sc pipeline.
// ---------------------------------------------------------------------------
__global__ __launch_bounds__(512) void decoder_loop11(
    const float* __restrict__ zemb,   // [3200][4096] (in d_out)
    const float* __restrict__ Wcomb,  // [2048][4096]
    const float* __restrict__ keys,   // [64][50][1024]
    const float* __restrict__ memory, // [64][50][1024]
    const float* __restrict__ c0,
    float* __restrict__ hcbuf,        // [50][HCSTR_] (in d_out)
    float* __restrict__ zp,           // [4][64][4096] (sc-ops only)
    float* __restrict__ hc_all,       // [64][50][2048] (plain)
    unsigned* flags)
{
    static __shared__ __attribute__((aligned(16))) char smem[153088];
    bf16_t* wfr = (bf16_t*)smem;                    // 131072 B frag store
    float*  tr  = (float*)(smem + 131072);          // [64][68] transpose
    float*  hs  = (float*)(smem + 148480);          // 1024
    float*  sc  = (float*)(smem + 152576);          // 64
    float*  al  = (float*)(smem + 152832);          // 64

    const int beta = blockIdx.x;
    const int tid  = threadIdx.x;

    const int nt = beta & 63, ks = beta >> 6;
    const int koff = ks * 512;
    const int c0c  = nt * 64;

    // ---- pack Wcomb slice [512 k][64 cols] -> LDS fragments (once) ----
    for (int i = tid; i < 512 * 64; i += 512) {
        const int k = i >> 6, col = i & 63;
        const float w = Wcomb[(size_t)(koff + k) * U4_ + c0c + col];
        const bf16_t hi = (bf16_t)w;
        const bf16_t lo = (bf16_t)(w - (float)hi);
        const int ntile = col >> 4, lane_lo = col & 15;
        const int kk = k >> 5, kr = k & 31;
        const int lane = (kr >> 3) * 16 + lane_lo, j = kr & 7;
        const int base = ((ntile * 16 + kk) * 2) * 512 + lane * 8 + j;
        wfr[base]       = hi;
        wfr[base + 512] = lo;
    }

    const int b  = beta;
    const int u2 = tid * 2;
    float creg[2] = {0.f, 0.f};
    if (beta < 64) {
        float2 cv = *(const float2*)&c0[b * U_ + u2];
        creg[0] = cv.x;
        creg[1] = cv.y;
    }
    __syncthreads();

    const int w  = tid >> 6, l = tid & 63;
    const int mt = w >> 1, ntb = (w & 1) * 2;
    const int arow = mt * 16 + (l & 15);
    const int aq   = l >> 4;
    const size_t abase = (size_t)arow * 2048 + koff + aq * 8;

    for (int t = 0; t < T_; ++t) {
        // ---------------- phase A (t>=1): zp = hcbuf[t-1] @ Wcomb (MFMA) ----
        if (t) {
            {   // wait on producer of my k-half
                const unsigned tgt = 8u * (unsigned)t;
                const unsigned* fb = (ks < 2) ? &flags[512] : &flags[768];
                if (tid < 8) {
                    const unsigned* f = fb + tid * 32;
                    while (scload_u(f) < tgt) __builtin_amdgcn_s_sleep(1);
                }
                __syncthreads();
                cbar();
            }

            const float* ap = &hcbuf[(size_t)(t - 1) * HCSTR_ + abase];

            f32x4 acc[2] = {};
            float4 ca0 = *(const float4*)&ap[0];
            float4 ca1 = *(const float4*)&ap[4];
#pragma unroll
            for (int kk = 0; kk < 16; ++kk) {
                float4 pa0, pa1;
                if (kk < 15) {
                    pa0 = *(const float4*)&ap[(kk + 1) * 32];
                    pa1 = *(const float4*)&ap[(kk + 1) * 32 + 4];
                }
                float xs[8] = {ca0.x, ca0.y, ca0.z, ca0.w,
                               ca1.x, ca1.y, ca1.z, ca1.w};
                bf16x8 ah, alv;
#pragma unroll
                for (int e = 0; e < 8; ++e) {
                    bf16_t h = (bf16_t)xs[e];
                    ah[e]  = h;
                    alv[e] = (bf16_t)(xs[e] - (float)h);
                }
#pragma unroll
                for (int nn = 0; nn < 2; ++nn) {
                    const int fb2 = (((ntb + nn) * 16 + kk) * 2) * 512 + l * 8;
                    bf16x8 bh = *(const bf16x8*)&wfr[fb2];
                    bf16x8 bl = *(const bf16x8*)&wfr[fb2 + 512];
                    acc[nn] = __builtin_amdgcn_mfma_f32_16x16x32_bf16(ah, bh, acc[nn], 0, 0, 0);
                    acc[nn] = __builtin_amdgcn_mfma_f32_16x16x32_bf16(ah, bl, acc[nn], 0, 0, 0);
                    acc[nn] = __builtin_amdgcn_mfma_f32_16x16x32_bf16(alv, bh, acc[nn], 0, 0, 0);
                }
                ca0 = pa0;
                ca1 = pa1;
            }

#pragma unroll
            for (int nn = 0; nn < 2; ++nn)
#pragma unroll
                for (int rr = 0; rr < 4; ++rr)
                    tr[(mt * 16 + (l >> 4) * 4 + rr) * 68 + (ntb + nn) * 16 + (l & 15)] =
                        acc[nn][rr];
            __syncthreads();

            {
                const int zb = tid >> 3, cg = (tid & 7) * 8;
                float4 r0 = *(const float4*)&tr[zb * 68 + cg];
                float4 r1 = *(const float4*)&tr[zb * 68 + cg + 4];
                float* zrow = &zp[((size_t)(ks * 64 + zb)) * U4_ + c0c + cg];
                scstore8(zrow + 0, r0.x, r0.y);
                scstore8(zrow + 2, r0.z, r0.w);
                scstore8(zrow + 4, r1.x, r1.y);
                scstore8(zrow + 6, r1.z, r1.w);
            }
            vm_drain();
            __syncthreads();
            if (tid == 0) scadd_u(&flags[(beta & 15) * 32]);   // zp group flag
        }

        // ---------------- phase BC: gates + attention (blocks < 64) ---------
        if (beta < 64) {
            if (t) {
                const unsigned tgt = 16u * (unsigned)t;
                if (tid < 16) {
                    const unsigned* f = &flags[tid * 32];
                    while (scload_u(f) < tgt) __builtin_amdgcn_s_sleep(1);
                }
                __syncthreads();
                cbar();
            }

            const float* ze = &zemb[((size_t)b * T_ + t) * U4_];
            float zgx[4], zgy[4];
#pragma unroll
            for (int g = 0; g < 4; ++g) {
                float2 a = *(const float2*)&ze[g * U_ + u2];
                zgx[g] = a.x;
                zgy[g] = a.y;
            }
#pragma unroll
            for (int s = 0; s < 4; ++s) {
#pragma unroll
                for (int g = 0; g < 4; ++g) {
                    float2 v = scload8(&zp[((size_t)s * 64 + b) * U4_ + g * U_ + u2]);
                    zgx[g] += v.x;
                    zgy[g] += v.y;
                }
            }

            const float six = 1.f / (1.f + expf(-zgx[0]));
            const float sfx = 1.f / (1.f + expf(-zgx[1]));
            const float tgx = tanhf(zgx[2]);
            const float sox = 1.f / (1.f + expf(-zgx[3]));
            const float cnx = sfx * creg[0] + six * tgx;
            creg[0] = cnx;
            const float hnx = sox * tanhf(cnx);

            const float siy = 1.f / (1.f + expf(-zgy[0]));
            const float sfy = 1.f / (1.f + expf(-zgy[1]));
            const float tgy = tanhf(zgy[2]);
            const float soy = 1.f / (1.f + expf(-zgy[3]));
            const float cny = sfy * creg[1] + siy * tgy;
            creg[1] = cny;
            const float hny = soy * tanhf(cny);

            float* hcb_t = &hcbuf[(size_t)t * HCSTR_];
            hs[u2]     = hnx;
            hs[u2 + 1] = hny;
            scstore8(&hcb_t[b * 2048 + u2], hnx, hny);
            *(float2*)&hc_all[((size_t)b * T_ + t) * 2048 + u2] =
                make_float2(hnx, hny);
            vm_drain();
            __syncthreads();
            if (tid == 0) scadd_u(&flags[512 + (b & 7) * 32]);  // h group flag

            const int lane = tid & 63, wv = tid >> 6;
            for (int s = wv; s < S_; s += 8) {
                const float* kp = &keys[((size_t)b * S_ + s) * U_ + lane * 16];
                const float* hp = &hs[lane * 16];
                float p = 0.f;
#pragma unroll
                for (int q = 0; q < 4; ++q) {
                    float4 kv = *(const float4*)&kp[q * 4];
                    float4 hv = *(const float4*)&hp[q * 4];
                    p = fmaf(hv.x, kv.x, p);
                    p = fmaf(hv.y, kv.y, p);
                    p = fmaf(hv.z, kv.z, p);
                    p = fmaf(hv.w, kv.w, p);
                }
#pragma unroll
                for (int off = 32; off > 0; off >>= 1)
                    p += __shfl_xor(p, off);
                if (lane == 0) sc[s] = p;
            }
            __syncthreads();

            if (tid < 64) {
                float v = (tid < S_) ? sc[tid] : -INFINITY;
                float m = v;
#pragma unroll
                for (int off = 32; off > 0; off >>= 1)
                    m = fmaxf(m, __shfl_xor(m, off));
                float e = (tid < S_) ? expf(v - m) : 0.f;
                float ssum = e;
#pragma unroll
                for (int off = 32; off > 0; off >>= 1)
                    ssum += __shfl_xor(ssum, off);
                if (tid < S_) al[tid] = e / ssum;
            }
            __syncthreads();

            {
                const float2* mp = (const float2*)&memory[(size_t)b * S_ * U_];
                float cx = 0.f, cy = 0.f;
#pragma unroll 10
                for (int s = 0; s < S_; ++s) {
                    float2 mv = mp[s * 512 + tid];
                    const float a = al[s];
                    cx = fmaf(a, mv.x, cx);
                    cy = fmaf(a, mv.y, cy);
                }
                scstore8(&hcb_t[b * 2048 + U_ + u2], cx, cy);
                *(float2*)&hc_all[((size_t)b * T_ + t) * 2048 + U_ + u2] =
                    make_float2(cx, cy);
            }
            vm_drain();
            __syncthreads();
            if (tid == 0) scadd_u(&flags[768 + (b & 7) * 32]);  // ctx group flag
        }
    }
}

// ---------------------------------------------------------------------------
// bf16 MFMA GEMM for Wo, DOUBLE-BUFFERED: C = A[3200][1024] @ Bt^T + bias.
// ---------------------------------------------------------------------------
__global__ __launch_bounds__(256) void gemm_wo_mfma3(
    const bf16_t* __restrict__ A,
    const bf16_t* __restrict__ Bt,
    const float*  __restrict__ bias,
    float* __restrict__ C)
{
    __shared__ bf16_t As[2][128][40];
    __shared__ bf16_t Bs[2][128][40];

    const int n0  = blockIdx.x * 128;
    const int m0  = blockIdx.y * 128;
    const int tid = threadIdx.x;
    const int wave = tid >> 6, lane = tid & 63;
    const int wr = wave >> 1, wc = wave & 1;
    const int lr = lane & 15;
    const int lk = lane >> 4;

    f32x4 acc[4][4] = {};

    const int ar = tid >> 1, ak = (tid & 1) * 16;
    const bf16_t* apb = &A[(size_t)(m0 + ar) * U_ + ak];
    const bf16_t* bpb = &Bt[(size_t)(n0 + ar) * U_ + ak];

    {
        *(bf16x8*)&As[0][ar][ak]     = *(const bf16x8*)&apb[0];
        *(bf16x8*)&As[0][ar][ak + 8] = *(const bf16x8*)&apb[8];
        *(bf16x8*)&Bs[0][ar][ak]     = *(const bf16x8*)&bpb[0];
        *(bf16x8*)&Bs[0][ar][ak + 8] = *(const bf16x8*)&bpb[8];
    }
    __syncthreads();

    for (int k0 = 0; k0 < U_; k0 += 32) {
        const int cur = (k0 >> 5) & 1;
        bf16x8 na0, na1, nb0, nb1;
        const bool more = (k0 + 32 < U_);
        if (more) {
            na0 = *(const bf16x8*)&apb[k0 + 32];
            na1 = *(const bf16x8*)&apb[k0 + 40];
            nb0 = *(const bf16x8*)&bpb[k0 + 32];
            nb1 = *(const bf16x8*)&bpb[k0 + 40];
        }

        bf16x8 af[4], bf[4];
#pragma unroll
        for (int m = 0; m < 4; ++m)
            af[m] = *(const bf16x8*)&As[cur][wr * 64 + m * 16 + lr][lk * 8];
#pragma unroll
        for (int n = 0; n < 4; ++n)
            bf[n] = *(const bf16x8*)&Bs[cur][wc * 64 + n * 16 + lr][lk * 8];
#pragma unroll
        for (int m = 0; m < 4; ++m)
#pragma unroll
            for (int n = 0; n < 4; ++n)
                acc[m][n] = __builtin_amdgcn_mfma_f32_16x16x32_bf16(
                    af[m], bf[n], acc[m][n], 0, 0, 0);

        if (more) {
            *(bf16x8*)&As[cur ^ 1][ar][ak]     = na0;
            *(bf16x8*)&As[cur ^ 1][ar][ak + 8] = na1;
            *(bf16x8*)&Bs[cur ^ 1][ar][ak]     = nb0;
            *(bf16x8*)&Bs[cur ^ 1][ar][ak + 8] = nb1;
        }
        __syncthreads();
    }

#pragma unroll
    for (int m = 0; m < 4; ++m) {
        const int row = m0 + wr * 64 + m * 16 + lk * 4;
#pragma unroll
        for (int n = 0; n < 4; ++n) {
            const int col = n0 + wc * 64 + n * 16 + lr;
            if (col < V_) {
                const float bb = bias[col];
#pragma unroll
                for (int r = 0; r < 4; ++r)
                    C[(size_t)(row + r) * V_ + col] = acc[m][n][r] + bb;
            }
        }
    }
}

// ---------------------------------------------------------------------------
extern "C" void kernel_launch(void* const* d_in, const int* in_sizes, int n_in,
                              void* d_out, int out_size, void* d_ws, size_t ws_size,
                              hipStream_t stream)
{
    const int*   tokens = (const int*)  d_in[0];
    const float* memory = (const float*)d_in[1];
    const float* h0     = (const float*)d_in[2];
    const float* c0     = (const float*)d_in[3];
    const float* emb    = (const float*)d_in[4];
    const float* Wx     = (const float*)d_in[5];
    const float* Uh     = (const float*)d_in[6];
    const float* bvec   = (const float*)d_in[7];
    const float* Wm     = (const float*)d_in[8];
    const float* Wa     = (const float*)d_in[9];
    const float* Wo     = (const float*)d_in[10];
    const float* bo     = (const float*)d_in[11];
    float* out = (float*)d_out;

    // ---- workspace layout (float units) ----
    float* ws = (float*)d_ws;
    size_t off = 0;
    float*   Wcomb  = ws + off; off += (size_t)2048 * U4_;      // 33.55 MB
    float*   keys   = ws + off; off += (size_t)B_ * S_ * U_;    // 13.11 MB
    float*   hc_all = ws + off; off += (size_t)B_ * T_ * 2048;  // 26.21 MB
    float*   zp     = ws + off; off += (size_t)4 * B_ * U4_;    //  4.19 MB
    float*   x_emb  = ws + off; off += (size_t)B_ * T_ * 128;   //  1.64 MB
    unsigned* flags = (unsigned*)(ws + off); off += 1024;       //  4 KB
    bf16_t*  wo_t   = (bf16_t*)(ws + off); off += (size_t)VP_ * 1024 / 2; // 61.6 MB

    // d_out-resident scratch (all dead before the final GEMM writes out):
    float* zemb   = out;                               // [3200][4096]  52.4 MB
    float* hcbuf  = out + (size_t)3200 * U4_;          // [50][HCSTR_]  26.2 MB
    float* wx_pad = out + (size_t)3200 * U4_ + (size_t)T_ * HCSTR_; // [128][4096]
    bf16_t* abf   = (bf16_t*)Wcomb;                    // post-loop alias

    (void)ws_size;
    (void)hipMemsetAsync(flags, 0, 1024 * sizeof(unsigned), stream);

    // ---- pre-loop ----
    gather_emb_pad<<<B_ * T_, 128, 0, stream>>>(tokens, emb, x_emb);
    pad_wx<<<dim3(U4_ / 256, 128), 256, 0, stream>>>(Wx, bvec, wx_pad);
    gemm_mfma_split<0><<<dim3(32, 25), 256, 0, stream>>>(
        x_emb, 128, wx_pad, U4_, zemb, U4_, 128);
    gemm_mfma_split<0><<<dim3(32, 16), 256, 0, stream>>>(
        Wa, U_, Wx + (size_t)E_ * U4_, U4_, Wcomb, U4_, U_);
    add_inplace<<<(1024 * U4_) / 256, 256, 0, stream>>>(Wcomb, Uh, 1024 * U4_);
    gemm_mfma_split<0><<<dim3(8, 25), 256, 0, stream>>>(
        memory, U_, Wm, U_, keys, U_, U_);
    zgemm_partial<<<dim3(64, 4), 256, 0, stream>>>(h0, U_, Uh, zp);
    transpose_wo<<<dim3(VP_ / 64, 1024 / 64), 256, 0, stream>>>(Wo, wo_t);

    // ---- persistent recurrent loop (r17 best-known) ----
    decoder_loop11<<<256, 512, 0, stream>>>(
        zemb, Wcomb, keys, memory, c0, hcbuf, zp, hc_all, flags);

    // ---- post-loop ----
    gemm_mfma_split<1><<<dim3(8, 25), 256, 0, stream>>>(
        hc_all, 2048, Wa, U_, (float*)abf, U_, 2048);
    gemm_wo_mfma3<<<dim3(VP_ / 128, 25), 256, 0, stream>>>(abf, wo_t, bo, out);
}